// Round 9
// baseline (232.313 us; speedup 1.0000x reference)
//
#include <hip/hip_runtime.h>
#include <hip/hip_bf16.h>
#include <cstddef>

#define NBATCH 16384
#define NX 256
#define NY 128
#define NU 128
#define NQ 128

// ---- workspace layout (float offsets) ----
#define WS_A2     131072    // A^2   (A = I-E computed on the fly)
#define WS_A4     196608    // A^4
#define WS_P2     327680    // (I+A)(I+A^2) = sum A^0..3
#define WS_P4     393216    // P2(I+A^4)    = sum A^0..7 ~= E^-1 (err ~3e-6)
#define WS_WDX    524288    // 256x512 = [Einv F | Einv B1 | Einv B2]
#define WS_BASE   655360    // NBATCH x 128
#define WS_W      2752512   // NBATCH x 128 (fp32 w)
#define WS_WCH    4849664   // Wcat hi: 384x512 bf16 (98304 floats)
#define WS_WCL    4947968   // Wcat lo
#define WS_WBH    5046272   // Wbase hi: 128x384 bf16 (24576 floats)
#define WS_WBL    5070848   // Wbase lo
#define WS_D11S   5095424   // 128x128 pre-scaled D11 + 128 cvec
// end: 5111936 floats = 20.4 MB

typedef __attribute__((ext_vector_type(8))) short bf8_t;   // 8 bf16 (4 VGPR)
typedef __attribute__((ext_vector_type(4))) float f4_t;    // MFMA acc

#define C2LOG2E 2.8853900817779268f   // 2*log2(e)

// ---------------------------------------------------------------------------
__device__ __forceinline__ void gload_lds16(const void* g, void* l) {
  __builtin_amdgcn_global_load_lds(
      (const __attribute__((address_space(1))) unsigned int*)g,
      (__attribute__((address_space(3))) unsigned int*)l, 16, 0, 0);
}

// split fp32 -> bf16 hi/lo
__device__ __forceinline__ void splitbf(float a, unsigned short& h, unsigned short& l) {
  __hip_bfloat16 hb = __float2bfloat16(a);
  float hf = __bfloat162float(hb);
  __hip_bfloat16 lb = __float2bfloat16(a - hf);
  h = __builtin_bit_cast(unsigned short, hb);
  l = __builtin_bit_cast(unsigned short, lb);
}

// ---------------------------------------------------------------------------
// C(256x256) = opA(A) @ opB(B) [+ opX(X)].  mode: 0 plain, 1 = I-M, 2 = 2I-M
__device__ __forceinline__ void smallmm_body(const float* __restrict__ A,
                                             const float* __restrict__ B,
                                             const float* __restrict__ X,
                                             float* __restrict__ C,
                                             int modeA, int modeB, int modeX) {
  __shared__ float As[32][36];
  __shared__ float Bs[32][36];
  int tid = threadIdx.x;
  int tx = tid & 15, ty = tid >> 4;
  int r0 = blockIdx.x * 32, c0 = blockIdx.y * 32;
  int lr = tid >> 3, lc = (tid & 7) * 4;
  float acc00 = 0.f, acc01 = 0.f, acc10 = 0.f, acc11 = 0.f;
  for (int k0 = 0; k0 < 256; k0 += 32) {
    float4 a4 = *(const float4*)&A[(size_t)(r0 + lr) * 256 + k0 + lc];
    float4 b4 = *(const float4*)&B[(size_t)(k0 + lr) * 256 + c0 + lc];
    if (modeA) {
      float av[4] = {a4.x, a4.y, a4.z, a4.w};
#pragma unroll
      for (int q = 0; q < 4; ++q) {
        float d = (r0 + lr == k0 + lc + q) ? 1.0f : 0.0f;
        av[q] = (modeA == 1) ? d - av[q] : 2.0f * d - av[q];
      }
      a4.x = av[0]; a4.y = av[1]; a4.z = av[2]; a4.w = av[3];
    }
    if (modeB) {
      float bvv[4] = {b4.x, b4.y, b4.z, b4.w};
#pragma unroll
      for (int q = 0; q < 4; ++q) {
        float d = (k0 + lr == c0 + lc + q) ? 1.0f : 0.0f;
        bvv[q] = (modeB == 1) ? d - bvv[q] : 2.0f * d - bvv[q];
      }
      b4.x = bvv[0]; b4.y = bvv[1]; b4.z = bvv[2]; b4.w = bvv[3];
    }
    __syncthreads();
    As[lr][lc+0] = a4.x; As[lr][lc+1] = a4.y; As[lr][lc+2] = a4.z; As[lr][lc+3] = a4.w;
    Bs[lr][lc+0] = b4.x; Bs[lr][lc+1] = b4.y; Bs[lr][lc+2] = b4.z; Bs[lr][lc+3] = b4.w;
    __syncthreads();
#pragma unroll
    for (int kk = 0; kk < 32; ++kk) {
      float a0 = As[ty*2+0][kk], a1 = As[ty*2+1][kk];
      float b0 = Bs[kk][tx*2+0], b1 = Bs[kk][tx*2+1];
      acc00 += a0*b0; acc01 += a0*b1; acc10 += a1*b0; acc11 += a1*b1;
    }
  }
  int r = r0 + ty*2, c = c0 + tx*2;
  if (modeX) {
#pragma unroll
    for (int i = 0; i < 2; ++i)
#pragma unroll
      for (int j = 0; j < 2; ++j) {
        float xv = X[(size_t)(r+i)*256 + c+j];
        float d = (r+i == c+j) ? 1.0f : 0.0f;
        float add = (modeX == 1) ? xv : 2.0f * d - xv;
        if (i==0 && j==0) acc00 += add;
        if (i==0 && j==1) acc01 += add;
        if (i==1 && j==0) acc10 += add;
        if (i==1 && j==1) acc11 += add;
      }
  }
  C[(size_t)r*256 + c]       = acc00; C[(size_t)r*256 + c+1]     = acc01;
  C[(size_t)(r+1)*256 + c]   = acc10; C[(size_t)(r+1)*256 + c+1] = acc11;
}

__global__ __launch_bounds__(256) void k_mm(const float* A, const float* B,
                                            const float* X, float* C,
                                            int mA, int mB, int mX) {
  smallmm_body(A, B, X, C, mA, mB, mX);
}

// z=0: P2 = (2I-E) + (2I-E)@A2 ; z=1: A4 = A2@A2   (both depend only on E,A2)
__global__ __launch_bounds__(256) void k_mm_dual(const float* E, const float* A2,
                                                 float* P2, float* A4) {
  if (blockIdx.z == 0) smallmm_body(E, A2, E, P2, 2, 0, 2);
  else                 smallmm_body(A2, A2, nullptr, A4, 0, 0, 0);
}

// ---------------------------------------------------------------------------
// Wdx(256x512) = P @ [F | B1 | B2]
__global__ __launch_bounds__(256) void k_wdx(const float* __restrict__ P,
                                             const float* __restrict__ F,
                                             const float* __restrict__ B1,
                                             const float* __restrict__ B2,
                                             float* __restrict__ Wdx) {
  __shared__ float As[32][36];
  __shared__ float Bs[32][36];
  int tid = threadIdx.x;
  int tx = tid & 15, ty = tid >> 4;
  int r0 = blockIdx.x * 32, c0 = blockIdx.y * 32;
  const float* B; int ldb, cb;
  if (c0 < 256)      { B = F;  ldb = 256; cb = c0; }
  else if (c0 < 384) { B = B1; ldb = 128; cb = c0 - 256; }
  else               { B = B2; ldb = 128; cb = c0 - 384; }
  int lr = tid >> 3, lc = (tid & 7) * 4;
  float acc00 = 0.f, acc01 = 0.f, acc10 = 0.f, acc11 = 0.f;
  for (int k0 = 0; k0 < 256; k0 += 32) {
    float4 a4 = *(const float4*)&P[(size_t)(r0 + lr) * 256 + k0 + lc];
    float4 b4 = *(const float4*)&B[(size_t)(k0 + lr) * ldb + cb + lc];
    __syncthreads();
    As[lr][lc+0] = a4.x; As[lr][lc+1] = a4.y; As[lr][lc+2] = a4.z; As[lr][lc+3] = a4.w;
    Bs[lr][lc+0] = b4.x; Bs[lr][lc+1] = b4.y; Bs[lr][lc+2] = b4.z; Bs[lr][lc+3] = b4.w;
    __syncthreads();
#pragma unroll
    for (int kk = 0; kk < 32; ++kk) {
      float a0 = As[ty*2+0][kk], a1 = As[ty*2+1][kk];
      float b0 = Bs[kk][tx*2+0], b1 = Bs[kk][tx*2+1];
      acc00 += a0*b0; acc01 += a0*b1; acc10 += a1*b0; acc11 += a1*b1;
    }
  }
  int r = r0 + ty*2, c = c0 + tx*2;
  Wdx[(size_t)r*512 + c]       = acc00; Wdx[(size_t)r*512 + c+1]     = acc01;
  Wdx[(size_t)(r+1)*512 + c]   = acc10; Wdx[(size_t)(r+1)*512 + c+1] = acc11;
}

// ---------------------------------------------------------------------------
// Preconvert weights + D11s prescale + cvec (fused).
__global__ __launch_bounds__(256) void k_wprep(const float* __restrict__ Wdx,
                                               const float* __restrict__ C2,
                                               const float* __restrict__ D21,
                                               const float* __restrict__ D22,
                                               const float* __restrict__ C1,
                                               const float* __restrict__ D12,
                                               const float* __restrict__ D11,
                                               const float* __restrict__ Lam,
                                               ushort* __restrict__ Wh,
                                               ushort* __restrict__ Wl,
                                               ushort* __restrict__ Wbh,
                                               ushort* __restrict__ Wbl,
                                               float* __restrict__ D11s) {
  int i = blockIdx.x * 256 + threadIdx.x;
  if (i < 384 * 512) {
    int n = i >> 9, k = i & 511;
    float v;
    if (n < 256) v = Wdx[(size_t)n * 512 + k];
    else {
      int nn = n - 256;
      if (k < 256)      v = C2[(size_t)nn * 256 + k];
      else if (k < 384) v = D21[(size_t)nn * 128 + (k - 256)];
      else              v = D22[(size_t)nn * 128 + (k - 384)];
    }
    unsigned short h, l; splitbf(v, h, l);
    Wh[i] = h; Wl[i] = l;
  } else if (i < 384 * 512 + 128 * 384) {
    int j = i - 384 * 512;
    int n = j / 384, k = j - n * 384;
    float v = (k < 256) ? C1[(size_t)n * 256 + k] : D12[(size_t)n * 128 + (k - 256)];
    unsigned short h, l; splitbf(v, h, l);
    Wbh[j] = h; Wbl[j] = l;
  } else if (i < 384 * 512 + 128 * 384 + 128 * 128) {
    int j2 = i - (384 * 512 + 128 * 384);
    int jr = j2 >> 7;
    D11s[j2] = D11[j2] * (C2LOG2E / Lam[jr]);
  } else if (i < 384 * 512 + 128 * 384 + 128 * 128 + 128) {
    int i3 = i - (384 * 512 + 128 * 384 + 128 * 128);
    D11s[128 * 128 + i3] = C2LOG2E / Lam[i3];
  }
}

// ---------------------------------------------------------------------------
// Split-bf16 MFMA GEMM v3: BM=64, BN in {32,64}. 256 thr / 4 waves.
// BN=64: wave -> 32x32 out (ms 0..1, ns 0..1). BN=32: wave -> 16x32 (ms=0, ns 0..1).
// LDS row = 128B = [32 hi bf16 | 32 lo bf16] = 8 chunks of 16B, chunk c at
// byte ((c ^ (row&7))<<4). A reg-staged+split in-kernel; B via global_load_lds
// with inverse-swizzled per-lane source (linear LDS dest). A(k+1) prefetch held
// in flight across the barrier via counted vmcnt(2) (B issued first = oldest).
template <int KTOT, bool FINAL, int BN>
__global__ __launch_bounds__(256) void k_gemm3(const float* __restrict__ x,
                                               const float* __restrict__ u,
                                               const float* __restrict__ w,
                                               const ushort* __restrict__ Wh,
                                               const ushort* __restrict__ Wl,
                                               const float* __restrict__ bv,
                                               float* __restrict__ out) {
  constexpr int MS = (BN == 64) ? 2 : 1;   // 16-row frags per wave
  constexpr int NS = 2;                     // 16-col frags per wave
  __shared__ __align__(16) ushort sA[64 * 64];        // 8 KB
  __shared__ __align__(16) ushort sB[BN * 64];        // 8 or 4 KB
  const int tid  = threadIdx.x;
  const int lane = tid & 63, wav = tid >> 6;
  const int wrow0 = (BN == 64) ? (wav >> 1) * 32 : wav * 16;
  const int wcol0 = (BN == 64) ? (wav & 1) * 32 : 0;
  const int row0 = blockIdx.x * 64;
  const int n0   = blockIdx.y * BN;
  const int fr = lane & 15, fc = lane >> 4;

  // A staging: thread covers row tid>>2 (0..63), k-chunk (tid&3) [8 fp32]
  const int arow = tid >> 2;
  const int ach  = tid & 3;

  f4_t acc[MS][NS];
#pragma unroll
  for (int i = 0; i < MS; ++i)
#pragma unroll
    for (int j = 0; j < NS; ++j) acc[i][j] = f4_t{0.f, 0.f, 0.f, 0.f};

  float4 ar[2];
#define LOAD_A(K0)                                                    \
  {                                                                   \
    int kseg = (K0) + ach * 8;                                        \
    size_t gr = (size_t)(row0 + arow);                                \
    const float* ap0;                                                 \
    if (FINAL) {                                                      \
      if (kseg < 256)      ap0 = x + gr * 256 + kseg;                 \
      else if (kseg < 384) ap0 = w + gr * 128 + (kseg - 256);         \
      else                 ap0 = u + gr * 128 + (kseg - 384);         \
    } else {                                                          \
      if (kseg < 256)      ap0 = x + gr * 256 + kseg;                 \
      else                 ap0 = u + gr * 128 + (kseg - 256);         \
    }                                                                 \
    ar[0] = *(const float4*)ap0;                                      \
    ar[1] = *(const float4*)(ap0 + 4);                                \
  }

  const int NK = KTOT / 32;
  LOAD_A(0);

  for (int ks = 0; ks < NK; ++ks) {
    const int k0 = ks * 32;
    __syncthreads();   // previous step's LDS consumers done

    // ---- stage A(k): split 8 fp32 -> hi/lo 16B chunks, swizzled ----
    {
      unsigned short h[8], l[8];
      splitbf(ar[0].x, h[0], l[0]); splitbf(ar[0].y, h[1], l[1]);
      splitbf(ar[0].z, h[2], l[2]); splitbf(ar[0].w, h[3], l[3]);
      splitbf(ar[1].x, h[4], l[4]); splitbf(ar[1].y, h[5], l[5]);
      splitbf(ar[1].z, h[6], l[6]); splitbf(ar[1].w, h[7], l[7]);
      uint4 hv, lv;
      hv.x = (unsigned)h[0] | ((unsigned)h[1] << 16);
      hv.y = (unsigned)h[2] | ((unsigned)h[3] << 16);
      hv.z = (unsigned)h[4] | ((unsigned)h[5] << 16);
      hv.w = (unsigned)h[6] | ((unsigned)h[7] << 16);
      lv.x = (unsigned)l[0] | ((unsigned)l[1] << 16);
      lv.y = (unsigned)l[2] | ((unsigned)l[3] << 16);
      lv.z = (unsigned)l[4] | ((unsigned)l[5] << 16);
      lv.w = (unsigned)l[6] | ((unsigned)l[7] << 16);
      char* rb = (char*)&sA[arow * 64];
      *(uint4*)(rb + (((ach    ) ^ (arow & 7)) << 4)) = hv;
      *(uint4*)(rb + (((ach + 4) ^ (arow & 7)) << 4)) = lv;
    }

    // ---- stage B(k) via global_load_lds (issued FIRST = oldest vmem) ----
#pragma unroll
    for (int i = 0; i < BN / 32; ++i) {
      int rbase = wav * (BN / 4) + i * 8;      // 8 rows per call
      int nloc  = rbase + (lane >> 3);
      int c     = lane & 7;
      int g     = c ^ (nloc & 7);              // inverse-swizzled source chunk
      const ushort* src = (g < 4)
          ? (Wh + (size_t)(n0 + nloc) * KTOT + k0 + g * 8)
          : (Wl + (size_t)(n0 + nloc) * KTOT + k0 + (g - 4) * 8);
      gload_lds16(src, &sB[rbase * 64]);
    }

    // ---- prefetch A(k+1); stays in flight across the barrier ----
    {
      int kpre = (ks + 1 < NK) ? k0 + 32 : k0;
      LOAD_A(kpre);
    }
    asm volatile("s_waitcnt vmcnt(2)" ::: "memory");  // drain B, keep 2 A loads
    __syncthreads();

    // ---- fragments + MFMA (3-product split) ----
    bf8_t ah[MS], al[MS], bh[NS], bl[NS];
#pragma unroll
    for (int ms = 0; ms < MS; ++ms) {
      int r = wrow0 + ms * 16 + fr;
      char* rb = (char*)&sA[r * 64];
      ah[ms] = *(const bf8_t*)(rb + (((fc    ) ^ (r & 7)) << 4));
      al[ms] = *(const bf8_t*)(rb + (((fc + 4) ^ (r & 7)) << 4));
    }
#pragma unroll
    for (int ns = 0; ns < NS; ++ns) {
      int n = wcol0 + ns * 16 + fr;
      char* rb = (char*)&sB[n * 64];
      bh[ns] = *(const bf8_t*)(rb + (((fc    ) ^ (n & 7)) << 4));
      bl[ns] = *(const bf8_t*)(rb + (((fc + 4) ^ (n & 7)) << 4));
    }
#pragma unroll
    for (int ns = 0; ns < NS; ++ns)
#pragma unroll
      for (int ms = 0; ms < MS; ++ms) {
        acc[ms][ns] = __builtin_amdgcn_mfma_f32_16x16x32_bf16(ah[ms], bh[ns], acc[ms][ns], 0, 0, 0);
        acc[ms][ns] = __builtin_amdgcn_mfma_f32_16x16x32_bf16(ah[ms], bl[ns], acc[ms][ns], 0, 0, 0);
        acc[ms][ns] = __builtin_amdgcn_mfma_f32_16x16x32_bf16(al[ms], bh[ns], acc[ms][ns], 0, 0, 0);
      }
  }
#undef LOAD_A

  // ---- epilogue: C/D layout col=lane&15 (fr), row=(lane>>4)*4+j (fc,j) ----
#pragma unroll
  for (int ms = 0; ms < MS; ++ms) {
#pragma unroll
    for (int ns = 0; ns < NS; ++ns) {
#pragma unroll
      for (int j = 0; j < 4; ++j) {
        int m = row0 + wrow0 + ms * 16 + fc * 4 + j;
        int n = n0 + wcol0 + ns * 16 + fr;
        float v = acc[ms][ns][j];
        if (FINAL) {
          if (n0 < 256) out[(size_t)m * 256 + n] = v;
          else          out[(size_t)NBATCH * 256 + (size_t)m * 128 + (n - 256)] = v;
        } else {
          out[(size_t)m * 128 + n] = v + bv[n];
        }
      }
    }
  }
}

// ---------------------------------------------------------------------------
// uniform-lane broadcast via v_readlane
__device__ __forceinline__ float rdlane(float v, int l) {
  return __builtin_bit_cast(float, __builtin_amdgcn_readlane(__builtin_bit_cast(int, v), l));
}

// Sequential tanh solve, prescaled t-space. WR=2 rows/wave, grid 2048
// -> 8 waves/SIMD (VGPR ~20) for latency hiding of the trans-pipe chain.
#define WR 2
__global__ __launch_bounds__(256) void k_wsolve(const float* __restrict__ baseo,
                                                const float* __restrict__ D11s,
                                                float* __restrict__ wout) {
  int tid = threadIdx.x;
  int lane = tid & 63, wave = tid >> 6;
  size_t rowbase = (size_t)blockIdx.x * (4 * WR) + (size_t)wave * WR;
  const float* drow0 = D11s + (size_t)lane * 128;
  const float* drow1 = D11s + (size_t)(64 + lane) * 128;
  const float* cvec  = D11s + 128 * 128;

  float t0[WR], t1[WR], w0[WR], w1[WR];
  float c0 = cvec[lane];
  float c1 = cvec[64 + lane];
#pragma unroll
  for (int r = 0; r < WR; ++r) {
    t0[r] = baseo[(rowbase + r) * 128 + lane] * c0;
    t1[r] = baseo[(rowbase + r) * 128 + 64 + lane] * c1;
    w0[r] = 0.f; w1[r] = 0.f;
  }
  float d0 = drow0[0];
  float d1 = drow1[0];
  for (int k = 0; k < 64; ++k) {
    int kn = k + 1;
    float nd0 = (kn < 64) ? drow0[kn] : 0.f;
    float nd1 = drow1[kn];
#pragma unroll
    for (int r = 0; r < WR; ++r) {
      float tk = rdlane(t0[r], k);
      float e  = __builtin_amdgcn_exp2f(tk);
      float wk = 1.0f - 2.0f * __builtin_amdgcn_rcpf(e + 1.0f);
      t0[r] += wk * d0;
      t1[r] += wk * d1;
      if (lane == k) w0[r] = wk;
    }
    d0 = nd0; d1 = nd1;
  }
  for (int k = 64; k < 128; ++k) {
    int kn = k + 1;
    float nd1 = (kn < 128) ? drow1[kn] : 0.f;
#pragma unroll
    for (int r = 0; r < WR; ++r) {
      float tk = rdlane(t1[r], k - 64);
      float e  = __builtin_amdgcn_exp2f(tk);
      float wk = 1.0f - 2.0f * __builtin_amdgcn_rcpf(e + 1.0f);
      t1[r] += wk * d1;
      if (lane == (k - 64)) w1[r] = wk;
    }
    d1 = nd1;
  }
#pragma unroll
  for (int r = 0; r < WR; ++r) {
    wout[(rowbase + r) * 128 + lane]      = w0[r];
    wout[(rowbase + r) * 128 + 64 + lane] = w1[r];
  }
}

// ---------------------------------------------------------------------------
extern "C" void kernel_launch(void* const* d_in, const int* in_sizes, int n_in,
                              void* d_out, int out_size, void* d_ws, size_t ws_size,
                              hipStream_t stream) {
  (void)in_sizes; (void)n_in; (void)out_size; (void)ws_size;
  const float* x   = (const float*)d_in[0];
  const float* u   = (const float*)d_in[1];
  const float* F   = (const float*)d_in[2];
  const float* B1  = (const float*)d_in[3];
  const float* B2  = (const float*)d_in[4];
  const float* C1  = (const float*)d_in[5];
  const float* C2  = (const float*)d_in[6];
  const float* D11 = (const float*)d_in[7];
  const float* D12 = (const float*)d_in[8];
  const float* D21 = (const float*)d_in[9];
  const float* D22 = (const float*)d_in[10];
  const float* E   = (const float*)d_in[11];
  const float* Lam = (const float*)d_in[12];
  const float* bv  = (const float*)d_in[13];
  float* out = (float*)d_out;
  float* ws  = (float*)d_ws;

  float* A2   = ws + WS_A2;
  float* A4   = ws + WS_A4;
  float* P2   = ws + WS_P2;
  float* P4   = ws + WS_P4;
  float* Wdx  = ws + WS_WDX;
  float* base = ws + WS_BASE;
  float* wbuf = ws + WS_W;
  ushort* Wch = (ushort*)(ws + WS_WCH);
  ushort* Wcl = (ushort*)(ws + WS_WCL);
  ushort* Wbh = (ushort*)(ws + WS_WBH);
  ushort* Wbl = (ushort*)(ws + WS_WBL);
  float* D11s = ws + WS_D11S;

  // E^-1 ~= sum A^0..7 = (I+A)(I+A^2)(I+A^4), A = I-E (||A||~0.2, err ~3e-6)
  k_mm<<<dim3(8, 8), 256, 0, stream>>>(E, E, nullptr, A2, 1, 1, 0);      // A2=(I-E)^2
  k_mm_dual<<<dim3(8, 8, 2), 256, 0, stream>>>(E, A2, P2, A4);           // P2, A4
  k_mm<<<dim3(8, 8), 256, 0, stream>>>(P2, A4, P2, P4, 0, 0, 1);         // P4 = E^-1
  k_wdx<<<dim3(8, 16), 256, 0, stream>>>(P4, F, B1, B2, Wdx);
  k_wprep<<<1025, 256, 0, stream>>>(Wdx, C2, D21, D22, C1, D12, D11, Lam,
                                    Wch, Wcl, Wbh, Wbl, D11s);

  // base = x@C1^T + u@D12^T + bv
  k_gemm3<384, false, 32><<<dim3(256, 4), 256, 0, stream>>>(x, u, nullptr, Wbh, Wbl, bv, base);
  // sequential tanh solve
  k_wsolve<<<2048, 256, 0, stream>>>(base, D11s, wbuf);
  // [dx|y] = [x|w|u] @ Wcat^T
  k_gemm3<512, true, 64><<<dim3(256, 6), 256, 0, stream>>>(x, u, wbuf, Wch, Wcl, nullptr, out);
}